// Round 10
// baseline (837.514 us; speedup 1.0000x reference)
//
#include <hip/hip_runtime.h>

#define N_NODES 100000
#define N_EDGES 1600000
#define NEG_SLOPE 0.01f
#define NPAD 102400
#define NBLK_SCAN 391   // ceil(100000/256)
#define NPART 16
#define PART_SZ 6250    // 16 * 6250 = 100000 exactly
#define CAPP 110000     // per-partition record capacity
#define BATCH 2048      // edges per pass-1 block
#define NBLK1 782       // ceil(1600000/2048)
#define NBKT 98         // 64-node buckets per partition (97*64+42 = 6250)
#define BKT_TOT 1568    // 16 * 98
#define RCAP3 1536      // staged records per agg_bf3 block (avg 1024)

// ---- bf16 pack/unpack (RNE) ----
__device__ inline unsigned pk_bf2(float lo, float hi) {
    unsigned a = __builtin_bit_cast(unsigned, lo);
    unsigned b = __builtin_bit_cast(unsigned, hi);
    a = (a + 0x7fffu + ((a >> 16) & 1u)) >> 16;
    b = (b + 0x7fffu + ((b >> 16) & 1u)) >> 16;
    return a | (b << 16);
}
__device__ inline float ub_lo(unsigned u) { return __builtin_bit_cast(float, u << 16); }
__device__ inline float ub_hi(unsigned u) { return __builtin_bit_cast(float, u & 0xffff0000u); }

// ---------------------------------------------------------------------------
__global__ void k_ginit(int* __restrict__ gcur) {
    int i = threadIdx.x;
    if (i < NPART) gcur[i] = i * CAPP;
}

__global__ void k_dinv(const int* __restrict__ deg, float* __restrict__ dinv) {
    int i = blockIdx.x * 256 + threadIdx.x;
    if (i < N_NODES) dinv[i] = rsqrtf((float)(deg[i] + 1));  // +1 self loop
}

// bcur[g] = record base of bucket g (from per-node exclusive scan)
__global__ void k_binit(const int* __restrict__ cur, int* __restrict__ bcur) {
    int g = blockIdx.x * 256 + threadIdx.x;
    if (g < BKT_TOT) {
        int p = g / NBKT, k = g - p * NBKT;
        bcur[g] = cur[p * PART_SZ + k * 64];
    }
}

// ---------------------------------------------------------------------------
// Pass 1: multisplit edges into 16 dst-partitions. Record = (dlocal<<17)|src.
// ---------------------------------------------------------------------------
__global__ __launch_bounds__(256) void k_pass1(const int* __restrict__ src,
                                               const int* __restrict__ dst,
                                               int* __restrict__ gcur,
                                               unsigned* __restrict__ part) {
    __shared__ int hist[NPART];
    __shared__ int scanb[NPART];
    __shared__ int gbase[NPART];
    __shared__ int run[NPART];
    __shared__ unsigned stage[BATCH];
    const int tid = threadIdx.x;
    const int e0 = blockIdx.x * BATCH;
    if (tid < NPART) hist[tid] = 0;
    __syncthreads();
    int dl[8], sv[8], bk[8];
#pragma unroll
    for (int i = 0; i < 8; ++i) {
        int e = e0 + i * 256 + tid;
        if (e < N_EDGES) {
            int d = dst[e];
            sv[i] = src[e];
            bk[i] = d / PART_SZ;
            dl[i] = d - bk[i] * PART_SZ;
            atomicAdd(&hist[bk[i]], 1);
        } else bk[i] = -1;
    }
    __syncthreads();
    if (tid == 0) {
        int acc = 0;
        for (int b = 0; b < NPART; ++b) { scanb[b] = acc; acc += hist[b]; }
    }
    __syncthreads();
    if (tid < NPART) {
        gbase[tid] = atomicAdd(&gcur[tid], hist[tid]);
        run[tid] = 0;
    }
    __syncthreads();
#pragma unroll
    for (int i = 0; i < 8; ++i) {
        if (bk[i] >= 0) {
            int rank = atomicAdd(&run[bk[i]], 1);
            stage[scanb[bk[i]] + rank] = ((unsigned)dl[i] << 17) | (unsigned)sv[i];
        }
    }
    __syncthreads();
    for (int b = 0; b < NPART; ++b) {
        int len = hist[b], sb = scanb[b], gb = gbase[b];
        int lim = (b + 1) * CAPP - gb;
        if (len > lim) len = lim;
        for (int i = tid; i < len; i += 256)
            part[gb + i] = stage[sb + i];
    }
}

// ---------------------------------------------------------------------------
// Degree count from partition records (L2-resident 25KB atomic window).
// ---------------------------------------------------------------------------
__global__ __launch_bounds__(256) void k_degp(const unsigned* __restrict__ part,
                                              const int* __restrict__ gcur,
                                              int* __restrict__ deg) {
    const int p = blockIdx.x & (NPART - 1);
    const int q = blockIdx.x >> 4;
    const int base = p * CAPP;
    int end = gcur[p]; if (end > base + CAPP) end = base + CAPP;
    const int stride = (gridDim.x >> 4) * 256;
    for (int i = base + q * 256 + threadIdx.x; i < end; i += stride) {
        unsigned r = part[i];
        atomicAdd(&deg[p * PART_SZ + (r >> 17)], 1);
    }
}

// ---------------------------------------------------------------------------
// Exclusive scan of in-degree into cur[]: 3-kernel block scan.
// ---------------------------------------------------------------------------
__global__ __launch_bounds__(256) void k_scan1(const int* __restrict__ deg,
                                               int* __restrict__ cur,
                                               int* __restrict__ bsum) {
    __shared__ int sd[256];
    int t = threadIdx.x;
    int gid = blockIdx.x * 256 + t;
    int v = (gid < N_NODES) ? deg[gid] : 0;
    sd[t] = v;
    __syncthreads();
    for (int off = 1; off < 256; off <<= 1) {
        int add = (t >= off) ? sd[t - off] : 0;
        __syncthreads();
        sd[t] += add;
        __syncthreads();
    }
    cur[gid] = sd[t] - v;  // exclusive
    if (t == 255) bsum[blockIdx.x] = sd[255];
}

__global__ __launch_bounds__(512) void k_scan2(int* __restrict__ bsum) {
    __shared__ int sd[512];
    int t = threadIdx.x;
    int v = (t < NBLK_SCAN) ? bsum[t] : 0;
    sd[t] = v;
    __syncthreads();
    for (int off = 1; off < 512; off <<= 1) {
        int add = (t >= off) ? sd[t - off] : 0;
        __syncthreads();
        sd[t] += add;
        __syncthreads();
    }
    if (t < NBLK_SCAN) bsum[t] = sd[t] - v;  // exclusive
}

__global__ void k_scan3(int* __restrict__ cur, const int* __restrict__ bsum) {
    int gid = blockIdx.x * 256 + threadIdx.x;
    cur[gid] += bsum[blockIdx.x];
}

// ---------------------------------------------------------------------------
// Pass 2b: bucket-granular sort. Block reads 2048 partition records
// (contiguous), reserves per-bucket chunks, writes records with precomputed
// w into csr8. Each chunk (~168B) is written by one block within ~µs ->
// lines collect their stores before eviction.
// ---------------------------------------------------------------------------
__global__ __launch_bounds__(256) void k_pass2b(const unsigned* __restrict__ part,
                                                const int* __restrict__ gcur,
                                                const float* __restrict__ dinv,
                                                int* __restrict__ bcur,
                                                uint2* __restrict__ csr8) {
    __shared__ int hist[NBKT];
    __shared__ int gbase[NBKT];
    __shared__ int run[NBKT];
    const int p = blockIdx.x & (NPART - 1);
    const int bq = blockIdx.x >> 4;
    const int tid = threadIdx.x;
    const int pbase = p * CAPP;
    int pend = gcur[p]; if (pend > pbase + CAPP) pend = pbase + CAPP;
    const int rs = pbase + bq * BATCH;
    int re = rs + BATCH; if (re > pend) re = pend;
    for (int i = tid; i < NBKT; i += 256) { hist[i] = 0; run[i] = 0; }
    __syncthreads();
    unsigned rec[8]; int bk[8];
#pragma unroll
    for (int i = 0; i < 8; ++i) {
        int idx = rs + i * 256 + tid;
        if (idx < re) {
            rec[i] = part[idx];
            bk[i] = rec[i] >> 23;            // dl>>6
            atomicAdd(&hist[bk[i]], 1);
        } else bk[i] = -1;
    }
    __syncthreads();
    if (tid < NBKT) gbase[tid] = atomicAdd(&bcur[p * NBKT + tid], hist[tid]);
    __syncthreads();
#pragma unroll
    for (int i = 0; i < 8; ++i) {
        if (bk[i] >= 0) {
            int rank = atomicAdd(&run[bk[i]], 1);
            unsigned r = rec[i];
            int s = r & 0x1FFFF;
            int node = p * PART_SZ + (int)(r >> 17);
            float w = dinv[s] * dinv[node];
            csr8[gbase[bk[i]] + rank] = make_uint2(r, __builtin_bit_cast(unsigned, w));
        }
    }
}

// ---------------------------------------------------------------------------
// hb[N,32] (packed 2xbf16) = X[N,128] @ W1[128,64], RNE-rounded to bf16.
// ---------------------------------------------------------------------------
__global__ __launch_bounds__(256) void k_gemm_bf(const float* __restrict__ X,
                                                 const float* __restrict__ W,
                                                 unsigned* __restrict__ Y) {
    __shared__ float ws[128 * 64];
    __shared__ __align__(16) float xs[16][128];
    const int tid = threadIdx.x;
    for (int i = tid; i < 128 * 64; i += 256) ws[i] = W[i];
    const int row0 = blockIdx.x * 16;
    for (int i = tid; i < 16 * 128; i += 256) {
        int r = i >> 7, k = i & 127;
        xs[r][k] = X[(size_t)(row0 + r) * 128 + k];
    }
    __syncthreads();
    const int c2 = tid & 31;
    const int rp = tid >> 5;
    float a00 = 0.f, a01 = 0.f, a10 = 0.f, a11 = 0.f;
    for (int k = 0; k < 128; k += 4) {
        float2 w0 = *(const float2*)&ws[(k + 0) * 64 + 2 * c2];
        float2 w1 = *(const float2*)&ws[(k + 1) * 64 + 2 * c2];
        float2 w2 = *(const float2*)&ws[(k + 2) * 64 + 2 * c2];
        float2 w3 = *(const float2*)&ws[(k + 3) * 64 + 2 * c2];
        float4 x0 = *(const float4*)&xs[2 * rp][k];
        float4 x1 = *(const float4*)&xs[2 * rp + 1][k];
        a00 = fmaf(x0.x, w0.x, a00); a01 = fmaf(x0.x, w0.y, a01);
        a10 = fmaf(x1.x, w0.x, a10); a11 = fmaf(x1.x, w0.y, a11);
        a00 = fmaf(x0.y, w1.x, a00); a01 = fmaf(x0.y, w1.y, a01);
        a10 = fmaf(x1.y, w1.x, a10); a11 = fmaf(x1.y, w1.y, a11);
        a00 = fmaf(x0.z, w2.x, a00); a01 = fmaf(x0.z, w2.y, a01);
        a10 = fmaf(x1.z, w2.x, a10); a11 = fmaf(x1.z, w2.y, a11);
        a00 = fmaf(x0.w, w3.x, a00); a01 = fmaf(x0.w, w3.y, a01);
        a10 = fmaf(x1.w, w3.x, a10); a11 = fmaf(x1.w, w3.y, a11);
    }
    Y[(size_t)(row0 + 2 * rp) * 32 + c2]     = pk_bf2(a00, a01);
    Y[(size_t)(row0 + 2 * rp + 1) * 32 + c2] = pk_bf2(a10, a11);
}

// ---------------------------------------------------------------------------
// Fold kernel: Wc[64,4] = W2[64,64] @ Wfc[64,4];  cfold[4] = b2^T Wfc + bfc
// ---------------------------------------------------------------------------
__global__ __launch_bounds__(256) void k_foldw(const float* __restrict__ W2,
                                               const float* __restrict__ b2,
                                               const float* __restrict__ Wfc,
                                               const float* __restrict__ bfc,
                                               float* __restrict__ Wc,
                                               float* __restrict__ cfold) {
    __shared__ float wf[64 * 4];
    int tid = threadIdx.x;
    wf[tid] = Wfc[tid];
    __syncthreads();
    int k = tid >> 2, c = tid & 3;
    float acc = 0.f;
#pragma unroll
    for (int j = 0; j < 64; ++j) acc = fmaf(W2[k * 64 + j], wf[j * 4 + c], acc);
    Wc[k * 4 + c] = acc;
    if (tid < 4) {
        float s = bfc[tid];
        for (int j = 0; j < 64; ++j) s = fmaf(b2[j], wf[j * 4 + tid], s);
        cfold[tid] = s;
    }
}

// ---------------------------------------------------------------------------
// Layer-1 aggregation v3: block = 64-node bucket. LDS f32 accumulator
// [64 nodes][64 feat]; half-wave per record (lane = feature pair, 2 LDS
// atomic adds). Epilogue fuses self + bias + leaky + Wc projection -> G.
// ---------------------------------------------------------------------------
__global__ __launch_bounds__(256) void k_agg_bf3(const int* __restrict__ cur,
                                                 const uint2* __restrict__ csr8,
                                                 const float* __restrict__ dinv,
                                                 const unsigned* __restrict__ hb,
                                                 const float* __restrict__ b,
                                                 const float* __restrict__ Wc,
                                                 float* __restrict__ G) {
    __shared__ float accum[64 * 64];   // 16 KiB
    __shared__ uint2 rec[RCAP3];       // 12 KiB
    __shared__ int sh[2];
    const int g = blockIdx.x;
    const int p = g / NBKT, k = g - p * NBKT;
    const int n0 = p * PART_SZ + k * 64;
    const int cnt = (k == NBKT - 1) ? (PART_SZ - (NBKT - 1) * 64) : 64;  // 42 or 64
    const int tid = threadIdx.x;
    if (tid == 0) { sh[0] = cur[n0]; sh[1] = cur[n0 + cnt]; }
    for (int i = tid; i < 64 * 64; i += 256) accum[i] = 0.f;
    __syncthreads();
    const int rbase = sh[0];
    const int total = sh[1] - rbase;
    const int staged = total < RCAP3 ? total : RCAP3;
    for (int i = tid; i < staged; i += 256) rec[i] = csr8[rbase + i];
    __syncthreads();
    const int lane = tid & 63, wv = tid >> 6;
    const int sub = lane & 31, half = lane >> 5;
    const int hw = wv * 2 + half;   // half-wave id 0..7
    int r = hw;
    for (; r + 8 < total; r += 16) {
        uint2 rc0 = (r < staged) ? rec[r] : csr8[rbase + r];
        uint2 rc1 = (r + 8 < staged) ? rec[r + 8] : csr8[rbase + r + 8];
        float w0 = __builtin_bit_cast(float, rc0.y);
        float w1 = __builtin_bit_cast(float, rc1.y);
        int nl0 = (rc0.x >> 17) & 63, nl1 = (rc1.x >> 17) & 63;
        unsigned u0 = hb[(size_t)(rc0.x & 0x1FFFF) * 32 + sub];
        unsigned u1 = hb[(size_t)(rc1.x & 0x1FFFF) * 32 + sub];
        atomicAdd(&accum[nl0 * 64 + 2 * sub],     ub_lo(u0) * w0);
        atomicAdd(&accum[nl0 * 64 + 2 * sub + 1], ub_hi(u0) * w0);
        atomicAdd(&accum[nl1 * 64 + 2 * sub],     ub_lo(u1) * w1);
        atomicAdd(&accum[nl1 * 64 + 2 * sub + 1], ub_hi(u1) * w1);
    }
    for (; r < total; r += 8) {
        uint2 rc = (r < staged) ? rec[r] : csr8[rbase + r];
        float w = __builtin_bit_cast(float, rc.y);
        int nl = (rc.x >> 17) & 63;
        unsigned u = hb[(size_t)(rc.x & 0x1FFFF) * 32 + sub];
        atomicAdd(&accum[nl * 64 + 2 * sub],     ub_lo(u) * w);
        atomicAdd(&accum[nl * 64 + 2 * sub + 1], ub_hi(u) * w);
    }
    __syncthreads();
    // epilogue: wave per node, lane = feature
    for (int nn = wv; nn < cnt; nn += 4) {
        const int node = n0 + nn;
        const float dv = dinv[node];
        unsigned u = hb[(size_t)node * 32 + (lane >> 1)];
        float sv = (lane & 1) ? ub_hi(u) : ub_lo(u);
        float h = accum[nn * 64 + lane] + sv * (dv * dv) + b[lane];
        h = (h >= 0.f) ? h : NEG_SLOPE * h;
        float4 wc = ((const float4*)Wc)[lane];
        float g0 = h * wc.x, g1 = h * wc.y, g2 = h * wc.z, g3 = h * wc.w;
#pragma unroll
        for (int m = 32; m >= 1; m >>= 1) {
            g0 += __shfl_xor(g0, m);
            g1 += __shfl_xor(g1, m);
            g2 += __shfl_xor(g2, m);
            g3 += __shfl_xor(g3, m);
        }
        if (lane == 0)
            *(float4*)&G[(size_t)node * 4] = make_float4(g0, g1, g2, g3);
    }
}

// ---------------------------------------------------------------------------
// Layer-2 aggregation: block = bucket; thread-per-record, 4 LDS atomic adds.
// ---------------------------------------------------------------------------
__global__ __launch_bounds__(256) void k_agg4b(const int* __restrict__ cur,
                                               const uint2* __restrict__ csr8,
                                               const float* __restrict__ dinv,
                                               const float4* __restrict__ G,
                                               const float* __restrict__ cfold,
                                               float4* __restrict__ out) {
    __shared__ float ac[64 * 4];
    __shared__ int sh[2];
    const int g = blockIdx.x;
    const int p = g / NBKT, k = g - p * NBKT;
    const int n0 = p * PART_SZ + k * 64;
    const int cnt = (k == NBKT - 1) ? (PART_SZ - (NBKT - 1) * 64) : 64;
    const int tid = threadIdx.x;
    if (tid == 0) { sh[0] = cur[n0]; sh[1] = cur[n0 + cnt]; }
    ac[tid] = 0.f;
    __syncthreads();
    const int rbase = sh[0];
    const int total = sh[1] - rbase;
    for (int r = tid; r < total; r += 256) {
        uint2 rc = csr8[rbase + r];
        float w = __builtin_bit_cast(float, rc.y);
        int nl = (rc.x >> 17) & 63;
        float4 gv = G[rc.x & 0x1FFFF];
        atomicAdd(&ac[nl * 4 + 0], gv.x * w);
        atomicAdd(&ac[nl * 4 + 1], gv.y * w);
        atomicAdd(&ac[nl * 4 + 2], gv.z * w);
        atomicAdd(&ac[nl * 4 + 3], gv.w * w);
    }
    __syncthreads();
    if (tid < cnt) {
        int node = n0 + tid;
        float dv = dinv[node];
        float w0 = dv * dv;
        float4 gv = G[node];
        float4 o;
        o.x = ac[tid * 4 + 0] + gv.x * w0 + cfold[0];
        o.y = ac[tid * 4 + 1] + gv.y * w0 + cfold[1];
        o.z = ac[tid * 4 + 2] + gv.z * w0 + cfold[2];
        o.w = ac[tid * 4 + 3] + gv.w * w0 + cfold[3];
        out[node] = o;
    }
}

// ---------------------------------------------------------------------------
extern "C" void kernel_launch(void* const* d_in, const int* in_sizes, int n_in,
                              void* d_out, int out_size, void* d_ws, size_t ws_size,
                              hipStream_t stream) {
    const float* x   = (const float*)d_in[0];
    const int*   ei  = (const int*)d_in[1];
    const float* W1  = (const float*)d_in[2];
    const float* b1  = (const float*)d_in[3];
    const float* W2  = (const float*)d_in[4];
    const float* b2  = (const float*)d_in[5];
    const float* Wfc = (const float*)d_in[6];
    const float* bfc = (const float*)d_in[7];
    float* out = (float*)d_out;

    // workspace layout (4B words)
    int*      deg   = (int*)d_ws;                    // NPAD
    int*      cur   = deg + NPAD;                    // NPAD
    float*    dinv  = (float*)(cur + NPAD);          // NPAD
    int*      bsum  = (int*)(dinv + NPAD);           // 1024
    float*    Wc    = (float*)(bsum + 1024);         // 256
    float*    cfold = Wc + 256;                      // 4 (pad to 256)
    int*      gcur  = (int*)(cfold + 256);           // 16 (pad to 256)
    int*      bcur  = gcur + 256;                    // BKT_TOT (pad to 2048)
    unsigned* part  = (unsigned*)(bcur + 2048);      // NPART*CAPP = 1760000
    uint2*    csr8  = (uint2*)(part + (size_t)NPART * CAPP);  // N_EDGES 8B
    unsigned* hb    = (unsigned*)(csr8 + N_EDGES);   // N*32 packed bf16 pairs
    float*    G     = (float*)(hb + (size_t)N_NODES * 32);    // N*4

    const int* src = ei;
    const int* dst = ei + N_EDGES;

    // init
    hipMemsetAsync(deg, 0, NPAD * sizeof(int), stream);
    k_ginit<<<1, 64, 0, stream>>>(gcur);

    // multisplit pass 1 (edges -> 16 partitions)
    k_pass1<<<NBLK1, 256, 0, stream>>>(src, dst, gcur, part);

    // degree, dinv
    k_degp<<<2048, 256, 0, stream>>>(part, gcur, deg);
    k_dinv<<<(N_NODES + 255) / 256, 256, 0, stream>>>(deg, dinv);

    // exclusive scan -> per-node offsets (bucket bases derive from this)
    k_scan1<<<NBLK_SCAN, 256, 0, stream>>>(deg, cur, bsum);
    k_scan2<<<1, 512, 0, stream>>>(bsum);
    k_scan3<<<NBLK_SCAN, 256, 0, stream>>>(cur, bsum);
    k_binit<<<(BKT_TOT + 255) / 256, 256, 0, stream>>>(cur, bcur);

    // pass 2b: bucket-granular sort with precomputed w
    k_pass2b<<<NPART * 50, 256, 0, stream>>>(part, gcur, dinv, bcur, csr8);

    // folded layer-2 weights
    k_foldw<<<1, 256, 0, stream>>>(W2, b2, Wfc, bfc, Wc, cfold);

    // ---- layer 1: hb = bf16(x @ W1); G = leaky(Agg(hb)+b1) @ Wc (fused) ----
    k_gemm_bf<<<N_NODES / 16, 256, 0, stream>>>(x, W1, hb);
    k_agg_bf3<<<BKT_TOT, 256, 0, stream>>>(cur, csr8, dinv, hb, b1, Wc, G);

    // ---- layer 2 (folded): out = Agg(G) + cfold ----
    k_agg4b<<<BKT_TOT, 256, 0, stream>>>(cur, csr8, dinv,
                                         (const float4*)G, cfold, (float4*)out);
}